// Round 8
// baseline (620.637 us; speedup 1.0000x reference)
//
#include <hip/hip_runtime.h>

// ExpFlow: scaling-and-squaring exponentiation of a velocity field.
// x: [N=2, C=3, 128^3] f32. u0 = x/32; 5x: u <- u + warp(u, id+u).
// SoA [N,3,D,H,W] f32 in global; chain x->A->B->A->B->d_out (d_out once).
//
// R8: LDS-staged gathers. R7 showed HBM fetch -42% with flat time -> limiter
// is L1<->L2 line traffic of divergent 8B gathers (~64B/line per miss).
// Each block owns an 8^3 tile, stages the 24x18x18 window (x margin >=7,
// y/z ~5) as fp16 AoS4 in LDS (62KB, 2 blocks/CU); gathers become aligned
// ds_read_b64 on the LDS pipe. Out-of-window lanes (displacement tails) take
// the exact R3 fp32 global path under exec-mask -> correctness is margin-
// independent. XCD-slab swizzle kept (bz pairs per XCD).

namespace {
constexpr int kPlane = 128 * 128 * 128;     // 2^21
constexpr int kVol   = 3 * kPlane;
constexpr int kTotalElems = 2 * kVol;       // floats per SoA buffer
constexpr float kScale0 = 1.0f / 32.0f;
constexpr int WX = 24, WY = 18, WZ = 18;    // staged window dims
constexpr int NVOX = WX * WY * WZ;          // 7776 voxels, 62208 B as f16x4
constexpr int NQ   = (WX / 4) * WY * WZ;    // 1944 x-quads
}

typedef float    f32x2 __attribute__((ext_vector_type(2)));
typedef float    f32x4 __attribute__((ext_vector_type(4)));
typedef _Float16 f16x4 __attribute__((ext_vector_type(4)));

template <bool SCALED>
__global__ __launch_bounds__(256) void step_kernel(const float* __restrict__ u,
                                                   float* __restrict__ out) {
    __shared__ f16x4 sm[NVOX];

    // block decode: b&7 = XCD (HW round-robin); each XCD owns 2 bz layers.
    int b   = blockIdx.x;              // 0..8191
    int xcd = b & 7;
    int s   = b >> 3;
    int n   = s >> 9;                  // batch
    int t   = s & 511;
    int bz  = (xcd << 1) | (t >> 8);   // 0..15
    int by  = (t >> 4) & 15;
    int bx  = t & 15;
    int ox = (bx << 3) - 8;            // x window origin (mult of 8 -> aligned)
    int oy = (by << 3) - 5;
    int oz = (bz << 3) - 5;

    const float* __restrict__ ub = u + (size_t)n * kVol;

    // ---- stage window into LDS (fp16 AoS4) ----
    bool interior = (bx >= 1) && (bx <= 14);   // x range [ox, ox+23] in-bounds
    for (int q = threadIdx.x; q < NQ; q += 256) {
        int qx  = q % 6;
        int row = q / 6;               // 0..323 = wz*WY + wy
        int wy  = row % WY;
        int wz  = row / WY;
        int gy = min(max(oy + wy, 0), 127);
        int gz = min(max(oz + wz, 0), 127);
        int rbase = (gz << 14) + (gy << 7);
        f32x4 va, vb, vc;
        if (interior) {
            const float* rp = ub + rbase + ox + (qx << 2);
            va = *(const f32x4*)rp;
            vb = *(const f32x4*)(rp + kPlane);
            vc = *(const f32x4*)(rp + 2 * kPlane);
        } else {
            #pragma unroll
            for (int k = 0; k < 4; ++k) {
                int gx = min(max(ox + (qx << 2) + k, 0), 127);
                va[k] = ub[rbase + gx];
                vb[k] = ub[kPlane + rbase + gx];
                vc[k] = ub[2 * kPlane + rbase + gx];
            }
        }
        if (SCALED) { va *= kScale0; vb *= kScale0; vc *= kScale0; }
        int slot = row * WX + (qx << 2);
        #pragma unroll
        for (int k = 0; k < 4; ++k)
            sm[slot + k] = f16x4{(_Float16)va[k], (_Float16)vb[k],
                                 (_Float16)vc[k], (_Float16)0.0f};
    }
    __syncthreads();

    // ---- compute 2 voxels (x-pair) per thread ----
    int tid = threadIdx.x;
    int w = (bx << 3) + ((tid & 3) << 1);
    int h = (by << 3) + ((tid >> 2) & 7);
    int d = (bz << 3) + (tid >> 5);
    int rr = (d << 14) + (h << 7) + w;

    f32x2 bvx = *(const f32x2*)(ub + rr);
    f32x2 bvy = *(const f32x2*)(ub + kPlane + rr);
    f32x2 bvz = *(const f32x2*)(ub + 2 * kPlane + rr);
    if (SCALED) { bvx *= kScale0; bvy *= kScale0; bvz *= kScale0; }

    float res[3][2];
    #pragma unroll
    for (int j = 0; j < 2; ++j) {
        float vx = (j == 0) ? bvx.x : bvx.y;
        float vy = (j == 0) ? bvy.x : bvy.y;
        float vz = (j == 0) ? bvz.x : bvz.y;
        float px = fminf(fmaxf((float)(w + j) + vx * 63.5f, 0.0f), 127.0f);
        float py = fminf(fmaxf((float)h       + vy * 63.5f, 0.0f), 127.0f);
        float pz = fminf(fmaxf((float)d       + vz * 63.5f, 0.0f), 127.0f);
        int x0 = min((int)floorf(px), 126);
        int y0 = min((int)floorf(py), 126);
        int z0 = min((int)floorf(pz), 126);
        float wx  = px - (float)x0, wy2 = py - (float)y0, wz2 = pz - (float)z0;
        float omx = 1.0f - wx, omy = 1.0f - wy2, omz = 1.0f - wz2;

        int lx0 = x0 - ox, ly0 = y0 - oy, lz0 = z0 - oz;
        bool ok = ((unsigned)lx0 <= (unsigned)(WX - 2)) &
                  ((unsigned)ly0 <= (unsigned)(WY - 2)) &
                  ((unsigned)lz0 <= (unsigned)(WZ - 2));
        if (ok) {
            int si = (lz0 * WY + ly0) * WX + lx0;
            f16x4 q000 = sm[si];                    f16x4 q001 = sm[si + 1];
            f16x4 q010 = sm[si + WX];               f16x4 q011 = sm[si + WX + 1];
            f16x4 q100 = sm[si + WY * WX];          f16x4 q101 = sm[si + WY * WX + 1];
            f16x4 q110 = sm[si + WY * WX + WX];     f16x4 q111 = sm[si + WY * WX + WX + 1];
            #pragma unroll
            for (int c = 0; c < 3; ++c) {
                float c00 = (float)q000[c] * omx + (float)q001[c] * wx;
                float c01 = (float)q010[c] * omx + (float)q011[c] * wx;
                float c10 = (float)q100[c] * omx + (float)q101[c] * wx;
                float c11 = (float)q110[c] * omx + (float)q111[c] * wx;
                float c0 = c00 * omy + c01 * wy2;
                float c1 = c10 * omy + c11 * wy2;
                float sres = c0 * omz + c1 * wz2;
                float basev = (c == 0) ? vx : (c == 1) ? vy : vz;
                res[c][j] = basev + sres;
            }
        } else {
            // exact R3 fp32 global fallback (rare: displacement tails)
            int o = (z0 << 14) + (y0 << 7) + x0;
            #pragma unroll
            for (int c = 0; c < 3; ++c) {
                const float* __restrict__ up = ub + c * kPlane;
                f32x2 v00 = *(const f32x2*)(up + o);
                f32x2 v01 = *(const f32x2*)(up + o + 128);
                f32x2 v10 = *(const f32x2*)(up + o + 16384);
                f32x2 v11 = *(const f32x2*)(up + o + 16512);
                if (SCALED) { v00 *= kScale0; v01 *= kScale0; v10 *= kScale0; v11 *= kScale0; }
                float c00 = v00.x * omx + v00.y * wx;
                float c01 = v01.x * omx + v01.y * wx;
                float c10 = v10.x * omx + v10.y * wx;
                float c11 = v11.x * omx + v11.y * wx;
                float c0 = c00 * omy + c01 * wy2;
                float c1 = c10 * omy + c11 * wy2;
                float sres = c0 * omz + c1 * wz2;
                float basev = (c == 0) ? vx : (c == 1) ? vy : vz;
                res[c][j] = basev + sres;
            }
        }
    }

    float* __restrict__ ob = out + (size_t)n * kVol;
    *(f32x2*)(ob + rr)              = f32x2{res[0][0], res[0][1]};
    *(f32x2*)(ob + kPlane + rr)     = f32x2{res[1][0], res[1][1]};
    *(f32x2*)(ob + 2 * kPlane + rr) = f32x2{res[2][0], res[2][1]};
}

extern "C" void kernel_launch(void* const* d_in, const int* in_sizes, int n_in,
                              void* d_out, int out_size, void* d_ws, size_t ws_size,
                              hipStream_t stream) {
    const float* x = (const float*)d_in[0];
    float* out = (float*)d_out;
    float* ws  = (float*)d_ws;

    const int grd = 8192;
    const size_t need = (size_t)2 * kTotalElems * sizeof(float);  // 100.7 MB

    if (ws_size >= need) {
        float* A = ws;
        float* B = ws + (size_t)kTotalElems;
        step_kernel<true ><<<grd, 256, 0, stream>>>(x, A);    // s1 (scale fused)
        step_kernel<false><<<grd, 256, 0, stream>>>(A, B);    // s2
        step_kernel<false><<<grd, 256, 0, stream>>>(B, A);    // s3
        step_kernel<false><<<grd, 256, 0, stream>>>(A, B);    // s4
        step_kernel<false><<<grd, 256, 0, stream>>>(B, out);  // s5 -> d_out (once)
    } else {
        step_kernel<true ><<<grd, 256, 0, stream>>>(x,   out);
        step_kernel<false><<<grd, 256, 0, stream>>>(out, ws);
        step_kernel<false><<<grd, 256, 0, stream>>>(ws,  out);
        step_kernel<false><<<grd, 256, 0, stream>>>(out, ws);
        step_kernel<false><<<grd, 256, 0, stream>>>(ws,  out);
    }
}